// Round 3
// baseline (968.082 us; speedup 1.0000x reference)
//
#include <hip/hip_runtime.h>
#include <math.h>

#define N_TOK 131072
#define DIM   64
#define QS    8
#define KS    1024

typedef _Float16 f16x8 __attribute__((ext_vector_type(8)));
typedef float    f32x4 __attribute__((ext_vector_type(4)));

#define RSCALE   2048.0f
#define RISCALE  4.8828125e-4f   // 2^-11

// split fp32 v into f16 limbs + scaled-hi: v ~= hi + lo*2^-11 ; hs = 2048*hi (exact)
#define SPLIT3(v, hi, lo, hs) { _Float16 _h = (_Float16)(v); (hi) = _h;        \
                                (lo) = (_Float16)(((v) - (float)_h) * RSCALE); \
                                (hs) = (_Float16)((float)_h * RSCALE); }

// ---- workspace layout G: 256 chunks, each 8448 B:
//   [0   .. 8191]  frag limbs: 8 sub-slots of 1KB (2 groups x {h0,h1,l0,l1})
//   [8192.. 8447]  dc2 tail: first 32 floats = -1024*||c||^2 (rest padding)
// Chunk c covers stage q = c>>5, codewords (c&31)*32 .. +31.
#define CHUNK_B 8448
#define CHUNK_H 4224     // _Float16 elements per chunk
#define DC2_H   4096     // half-offset of dc2 region (byte 8192)

// ---- pre-pass 1: codebook -> f16 limbs in MFMA fragment order.
// slot = (q*64+g)*4 + l*2 + h ; chunk c = slot>>3, sub = slot&7.
__global__ void conv_kernel(const float* __restrict__ cb, _Float16* __restrict__ G) {
    int t = blockIdx.x * blockDim.x + threadIdx.x;
    if (t >= 2048 * 64) return;
    const int lane = t & 63, slot = t >> 6;
    const int h = slot & 1, l = (slot >> 1) & 1, g = (slot >> 2) & 63, q = slot >> 8;
    const int cw = g * 16 + (lane & 15);
    const int d0 = h * 32 + (lane >> 4) * 8;
    const float* src = cb + ((size_t)q * KS + cw) * DIM + d0;
    f16x8 v;
#pragma unroll
    for (int j = 0; j < 8; ++j) {
        float c = src[j];
        _Float16 hi = (_Float16)c;
        v[j] = (l == 0) ? hi : (_Float16)((c - (float)hi) * RSCALE);
    }
    const int c = slot >> 3, w = slot & 7;
    *(f16x8*)(G + (size_t)c * CHUNK_H + w * 512 + lane * 8) = v;
}

// ---- pre-pass 2: dc2 seeds written into each chunk's tail ----
__global__ void dc2_kernel(const float* __restrict__ cb, float* __restrict__ Gf) {
    int i = blockIdx.x * blockDim.x + threadIdx.x;
    if (i < QS * KS) {
        const float* c = cb + (size_t)i * DIM;
        float s = 0.f;
#pragma unroll
        for (int d = 0; d < DIM; ++d) s = fmaf(c[d], c[d], s);
        const int q = i >> 10, k = i & 1023;
        const int ch = q * 32 + (k >> 5), j = k & 31;
        Gf[(size_t)ch * (CHUNK_B / 4) + (DC2_H / 2) + j] = -1024.0f * s;
    }
}

// ---- main: 16 tokens per wave, 2048 blocks x 256 thr, 8 blocks/CU (32 waves/CU).
// TLP is the latency-hiding mechanism: 8 waves/SIMD from 8 different blocks,
// barriers fully de-phased. Per chunk-iter: stage next chunk (global_load_lds),
// 8 frag ds_reads + 2 seed reads, 12 MFMAs (2 chains of 6), 1 barrier.
__global__ __launch_bounds__(256, 8)
void rvq_mfma_kernel(const float* __restrict__ x,
                     const float* __restrict__ cbf,
                     const _Float16* __restrict__ F,
                     float* __restrict__ out) {
    __shared__ __attribute__((aligned(16))) _Float16 smem[2 * CHUNK_H]; // 16.9 KB

    const int tid  = threadIdx.x;
    const int wave = tid >> 6;
    const int lane = tid & 63;
    const int quad = lane >> 4;
    const int m    = lane & 15;
    const int quad4 = quad * 4;

    const int tokA = blockIdx.x * 64 + wave * 16 + m;

    // token limbs (B-frag layout): th = hi, tl = 2048*(r-hi), ts = 2048*hi
    f16x8 th0, th1, tl0, tl1, ts0, ts1;
    {
        const float* xa = x + (size_t)tokA * DIM + quad * 8;
        f32x4 a0 = __builtin_nontemporal_load((const f32x4*)(xa));
        f32x4 a1 = __builtin_nontemporal_load((const f32x4*)(xa + 4));
        f32x4 a2 = __builtin_nontemporal_load((const f32x4*)(xa + 32));
        f32x4 a3 = __builtin_nontemporal_load((const f32x4*)(xa + 36));
#pragma unroll
        for (int j = 0; j < 4; ++j) {
            SPLIT3(a0[j], th0[j],   tl0[j],   ts0[j]);
            SPLIT3(a1[j], th0[j+4], tl0[j+4], ts0[j+4]);
            SPLIT3(a2[j], th1[j],   tl1[j],   ts1[j]);
            SPLIT3(a3[j], th1[j+4], tl1[j+4], ts1[j+4]);
        }
    }

// stage one chunk (8KB frags + 256B dc2 tail) into LDS buffer BUF.
// dest = wave-uniform base (+ lane*size implicit); global src is per-lane.
#define STAGE(GC, BUF) {                                                          \
        const char* _gs = (const char*)F + (size_t)(GC) * CHUNK_B                 \
                          + (wave << 10) + (lane << 4);                           \
        _Float16* _ld = smem + (BUF) * CHUNK_H + (wave << 9);                     \
        __builtin_amdgcn_global_load_lds(                                         \
            (const __attribute__((address_space(1))) void*)(_gs),                 \
            (__attribute__((address_space(3))) void*)(_ld), 16, 0, 0);            \
        __builtin_amdgcn_global_load_lds(                                         \
            (const __attribute__((address_space(1))) void*)(_gs + 4096),          \
            (__attribute__((address_space(3))) void*)(_ld + 2048), 16, 0, 0);     \
        if (wave == 0) {                                                          \
            const char* _gd = (const char*)F + (size_t)(GC) * CHUNK_B + 8192      \
                              + (lane << 2);                                      \
            __builtin_amdgcn_global_load_lds(                                     \
                (const __attribute__((address_space(1))) void*)_gd,               \
                (__attribute__((address_space(3))) void*)(smem + (BUF) * CHUNK_H  \
                                                          + DC2_H),               \
                4, 0, 0);                                                         \
        }                                                                         \
    }

// One group: single chain of 6 MFMA; acc IS the scaled score, no VALU combine.
#define COMPUTE(H0, H1, L0, L1, CIV, BASE) {                                       \
        f32x4 acc = __builtin_amdgcn_mfma_f32_16x16x32_f16(H0, ts0, CIV, 0,0,0);   \
        acc = __builtin_amdgcn_mfma_f32_16x16x32_f16(H1, ts1, acc, 0,0,0);         \
        acc = __builtin_amdgcn_mfma_f32_16x16x32_f16(L0, th0, acc, 0,0,0);         \
        acc = __builtin_amdgcn_mfma_f32_16x16x32_f16(L1, th1, acc, 0,0,0);         \
        acc = __builtin_amdgcn_mfma_f32_16x16x32_f16(H0, tl0, acc, 0,0,0);         \
        acc = __builtin_amdgcn_mfma_f32_16x16x32_f16(H1, tl1, acc, 0,0,0);         \
        _Pragma("unroll")                                                          \
        for (int i = 0; i < 4; ++i) {                                              \
            if (acc[i] > bv) { bv = acc[i]; bi = (BASE) + i; }                     \
        }                                                                          \
    }

    // prologue: stage chunk 0 of stage 0
    STAGE(0, 0);
    __syncthreads();
    int cur = 0;

    for (int q = 0; q < QS; ++q) {
        const float* cfq = cbf + (size_t)q * KS * DIM;

        float bv = -INFINITY;
        int   bi = 0;

        for (int ch = 0; ch < 32; ++ch) {
            const int gc = (q << 5) | ch;
            if (gc + 1 < 256) STAGE(gc + 1, cur ^ 1);   // prefetch next chunk

            const _Float16* L   = smem + cur * CHUNK_H + lane * 8;
            const float*    dcL = (const float*)(smem + cur * CHUNK_H + DC2_H);

            // group 0 (codewords ch*32 .. +15)
            {
                f32x4 ci = *(const f32x4*)(dcL + quad4);
                f16x8 h0 = *(const f16x8*)(L);
                f16x8 h1 = *(const f16x8*)(L + 512);
                f16x8 l0 = *(const f16x8*)(L + 1024);
                f16x8 l1 = *(const f16x8*)(L + 1536);
                COMPUTE(h0, h1, l0, l1, ci, ch * 32 + quad4);
            }
            // group 1 (codewords ch*32+16 .. +31)
            {
                f32x4 ci = *(const f32x4*)(dcL + 16 + quad4);
                f16x8 h0 = *(const f16x8*)(L + 2048);
                f16x8 h1 = *(const f16x8*)(L + 2560);
                f16x8 l0 = *(const f16x8*)(L + 3072);
                f16x8 l1 = *(const f16x8*)(L + 3584);
                COMPUTE(h0, h1, l0, l1, ci, ch * 32 + 16 + quad4);
            }

            // barrier doubles as vmcnt/lgkm drain: staged chunk gc+1 resident,
            // all waves done reading buffer cur.
            __syncthreads();
            cur ^= 1;
        }

        // reduce over the 4 quad-lanes holding the same token (disjoint codewords):
        // 2 shuffle steps. Tie-break: lowest index, matching jnp.argmin.
#pragma unroll
        for (int mask = 16; mask <= 32; mask <<= 1) {
            float ov = __shfl_xor(bv, mask, 64);
            int   oi = __shfl_xor(bi, mask, 64);
            if (ov > bv || (ov == bv && oi < bi)) { bv = ov; bi = oi; }
        }

        // index straight to global (every lane has its token's winner)
        if (quad == 0) out[(size_t)N_TOK * DIM + (size_t)tokA * QS + q] = (float)bi;

        // residual update: reconstruct r from limbs, subtract fp32 codeword, re-split
        float ls = 0.f;
        {
            const float* cp = cfq + (size_t)bi * DIM + quad * 8;
            f32x4 c0 = *(const f32x4*)(cp);
            f32x4 c1 = *(const f32x4*)(cp + 4);
            f32x4 c2 = *(const f32x4*)(cp + 32);
            f32x4 c3 = *(const f32x4*)(cp + 36);
#pragma unroll
            for (int j = 0; j < 4; ++j) {
                float v0 = fmaf(RISCALE, (float)tl0[j],   (float)th0[j])   - c0[j];
                float v1 = fmaf(RISCALE, (float)tl0[j+4], (float)th0[j+4]) - c1[j];
                float v2 = fmaf(RISCALE, (float)tl1[j],   (float)th1[j])   - c2[j];
                float v3 = fmaf(RISCALE, (float)tl1[j+4], (float)th1[j+4]) - c3[j];
                ls = fmaf(v0, v0, ls); ls = fmaf(v1, v1, ls);
                ls = fmaf(v2, v2, ls); ls = fmaf(v3, v3, ls);
                SPLIT3(v0, th0[j],   tl0[j],   ts0[j]);
                SPLIT3(v1, th0[j+4], tl0[j+4], ts0[j+4]);
                SPLIT3(v2, th1[j],   tl1[j],   ts1[j]);
                SPLIT3(v3, th1[j+4], tl1[j+4], ts1[j+4]);
            }
        }
#pragma unroll
        for (int mask = 1; mask <= 32; mask <<= 1) ls += __shfl_xor(ls, mask, 64);
        if (lane == 0)
            atomicAdd(out + (size_t)N_TOK * DIM + (size_t)N_TOK * QS + q,
                      ls * (1.0f / ((float)N_TOK * (float)DIM)));
    }

    // xq = x - r_final (reconstruct final residual from limbs)
    {
        const size_t ra = (size_t)tokA * DIM + quad * 8;
        f32x4 a0 = __builtin_nontemporal_load((const f32x4*)(x + ra));
        f32x4 a1 = __builtin_nontemporal_load((const f32x4*)(x + ra + 4));
        f32x4 a2 = __builtin_nontemporal_load((const f32x4*)(x + ra + 32));
        f32x4 a3 = __builtin_nontemporal_load((const f32x4*)(x + ra + 36));
#pragma unroll
        for (int j = 0; j < 4; ++j) {
            a0[j] -= fmaf(RISCALE, (float)tl0[j],   (float)th0[j]);
            a1[j] -= fmaf(RISCALE, (float)tl0[j+4], (float)th0[j+4]);
            a2[j] -= fmaf(RISCALE, (float)tl1[j],   (float)th1[j]);
            a3[j] -= fmaf(RISCALE, (float)tl1[j+4], (float)th1[j+4]);
        }
        __builtin_nontemporal_store(a0, (f32x4*)(out + ra));
        __builtin_nontemporal_store(a1, (f32x4*)(out + ra + 4));
        __builtin_nontemporal_store(a2, (f32x4*)(out + ra + 32));
        __builtin_nontemporal_store(a3, (f32x4*)(out + ra + 36));
    }
#undef COMPUTE
#undef STAGE
}

extern "C" void kernel_launch(void* const* d_in, const int* in_sizes, int n_in,
                              void* d_out, int out_size, void* d_ws, size_t ws_size,
                              hipStream_t stream) {
    const float* x   = (const float*)d_in[0];   // (N, D)
    const float* cb  = (const float*)d_in[1];   // (Q, K, D)
    float*       out = (float*)d_out;           // [xq | indices | losses]
    char*        ws  = (char*)d_ws;

    _Float16* G = (_Float16*)ws;   // 256 chunks x 8448 B = 2,162,688 B

    hipMemsetAsync(out + (size_t)N_TOK * DIM + (size_t)N_TOK * QS, 0,
                   QS * sizeof(float), stream);

    conv_kernel<<<512, 256, 0, stream>>>(cb, G);
    dc2_kernel<<<(QS * KS + 255) / 256, 256, 0, stream>>>(cb, (float*)ws);
    rvq_mfma_kernel<<<N_TOK / 64, 256, 0, stream>>>(x, cb, G, out);
}

// Round 4
// 598.478 us; speedup vs baseline: 1.6176x; 1.6176x over previous
//
#include <hip/hip_runtime.h>
#include <math.h>

#define N_TOK 131072
#define DIM   64
#define QS    8
#define KS    1024

typedef _Float16 f16x8 __attribute__((ext_vector_type(8)));
typedef float    f32x4 __attribute__((ext_vector_type(4)));

#define RSCALE   2048.0f
#define RISCALE  4.8828125e-4f   // 2^-11

// split fp32 v into f16 limbs + scaled-hi: v ~= hi + lo*2^-11 ; hs = 2048*hi (exact)
#define SPLIT3(v, hi, lo, hs) { _Float16 _h = (_Float16)(v); (hi) = _h;        \
                                (lo) = (_Float16)(((v) - (float)_h) * RSCALE); \
                                (hs) = (_Float16)((float)_h * RSCALE); }

// ---- workspace layout G: 128 chunks, each 16640 B:
//   [0    .. 16383]  frag limbs: 16 sub-slots of 1KB (4 groups x {h0,h1,l0,l1})
//   [16384.. 16639]  64 floats: -1024*||c||^2 seeds for the chunk's 64 codewords
// Chunk c covers stage q = c>>4, codewords (c&15)*64 .. +63.

// ---- pre-pass 1: codebook -> f16 limbs in MFMA fragment order.
// slot = (q*64+g)*4 + l*2 + h ; chunk c = slot>>4, sub = slot&15.
__global__ void conv_kernel(const float* __restrict__ cb, _Float16* __restrict__ G) {
    int t = blockIdx.x * blockDim.x + threadIdx.x;
    if (t >= 2048 * 64) return;
    const int lane = t & 63, slot = t >> 6;
    const int h = slot & 1, l = (slot >> 1) & 1, g = (slot >> 2) & 63, q = slot >> 8;
    const int cw = g * 16 + (lane & 15);
    const int d0 = h * 32 + (lane >> 4) * 8;
    const float* src = cb + ((size_t)q * KS + cw) * DIM + d0;
    f16x8 v;
#pragma unroll
    for (int j = 0; j < 8; ++j) {
        float c = src[j];
        _Float16 hi = (_Float16)c;
        v[j] = (l == 0) ? hi : (_Float16)((c - (float)hi) * RSCALE);
    }
    const int c = slot >> 4, w = slot & 15;
    *(f16x8*)(G + (size_t)c * 8320 + w * 512 + lane * 8) = v;
}

// ---- pre-pass 2: dc2 seeds written straight into each chunk's tail ----
__global__ void dc2_kernel(const float* __restrict__ cb, float* __restrict__ Gf) {
    int i = blockIdx.x * blockDim.x + threadIdx.x;
    if (i < QS * KS) {
        const float* c = cb + (size_t)i * DIM;
        float s = 0.f;
#pragma unroll
        for (int d = 0; d < DIM; ++d) s = fmaf(c[d], c[d], s);
        const int q = i >> 10, k = i & 1023;
        const int ch = q * 16 + (k >> 6), j = k & 63;
        Gf[(size_t)ch * 4160 + 4096 + j] = -1024.0f * s;
    }
}

#define CHUNK_B   16640     // bytes per chunk (16KB frags + 256B dc2)
#define CHUNK_H   8320      // _Float16 elements per chunk
#define DC2_OFF_H 8192      // half-offset of dc2 region (byte 16384)

__global__ __launch_bounds__(256, 4)
void rvq_mfma_kernel(const float* __restrict__ x,
                     const float* __restrict__ cbf,
                     const _Float16* __restrict__ F,
                     float* __restrict__ out) {
    __shared__ __attribute__((aligned(16))) _Float16 smem[2 * CHUNK_H]; // 33.3 KB

    const int tid  = threadIdx.x;
    const int wave = tid >> 6;
    const int lane = tid & 63;
    const int quad = lane >> 4;
    const int m    = lane & 15;
    const int quad4 = quad * 4;

    const int tokenBase = blockIdx.x * 128 + wave * 32;
    const int tokA = tokenBase + m, tokB = tokenBase + 16 + m;

    // token limbs (B-frag layout): th = hi, tl = 2048*(r-hi), ts = 2048*hi
    f16x8 thA0, thA1, tlA0, tlA1, tsA0, tsA1;
    f16x8 thB0, thB1, tlB0, tlB1, tsB0, tsB1;
    {
        const float* xa = x + (size_t)tokA * DIM + quad * 8;
        const float* xb = x + (size_t)tokB * DIM + quad * 8;
        f32x4 a0 = __builtin_nontemporal_load((const f32x4*)(xa));
        f32x4 a1 = __builtin_nontemporal_load((const f32x4*)(xa + 4));
        f32x4 a2 = __builtin_nontemporal_load((const f32x4*)(xa + 32));
        f32x4 a3 = __builtin_nontemporal_load((const f32x4*)(xa + 36));
        f32x4 b0 = __builtin_nontemporal_load((const f32x4*)(xb));
        f32x4 b1 = __builtin_nontemporal_load((const f32x4*)(xb + 4));
        f32x4 b2 = __builtin_nontemporal_load((const f32x4*)(xb + 32));
        f32x4 b3 = __builtin_nontemporal_load((const f32x4*)(xb + 36));
#pragma unroll
        for (int j = 0; j < 4; ++j) {
            SPLIT3(a0[j], thA0[j],   tlA0[j],   tsA0[j]);
            SPLIT3(a1[j], thA0[j+4], tlA0[j+4], tsA0[j+4]);
            SPLIT3(a2[j], thA1[j],   tlA1[j],   tsA1[j]);
            SPLIT3(a3[j], thA1[j+4], tlA1[j+4], tsA1[j+4]);
            SPLIT3(b0[j], thB0[j],   tlB0[j],   tsB0[j]);
            SPLIT3(b1[j], thB0[j+4], tlB0[j+4], tsB0[j+4]);
            SPLIT3(b2[j], thB1[j],   tlB1[j],   tsB1[j]);
            SPLIT3(b3[j], thB1[j+4], tlB1[j+4], tsB1[j+4]);
        }
    }

// stage one full chunk (frags + dc2 tail) of G into LDS buffer BUF.
// dest = wave-uniform base (+ lane*size implicit); global src is per-lane.
#define STAGE(GC, BUF) {                                                          \
        const char* _gs = (const char*)F + (size_t)(GC) * CHUNK_B                 \
                          + (wave << 10) + (lane << 4);                           \
        _Float16* _ld = smem + (BUF) * CHUNK_H + (wave << 9);                     \
        _Pragma("unroll")                                                         \
        for (int _j = 0; _j < 4; ++_j)                                            \
            __builtin_amdgcn_global_load_lds(                                     \
                (const __attribute__((address_space(1))) void*)(_gs + _j * 4096), \
                (__attribute__((address_space(3))) void*)(_ld + _j * 2048),       \
                16, 0, 0);                                                        \
        if (wave == 0) {                                                          \
            const char* _gd = (const char*)F + (size_t)(GC) * CHUNK_B + 16384     \
                              + (lane << 2);                                      \
            __builtin_amdgcn_global_load_lds(                                     \
                (const __attribute__((address_space(1))) void*)_gd,               \
                (__attribute__((address_space(3))) void*)(smem + (BUF) * CHUNK_H  \
                                                          + DC2_OFF_H),           \
                4, 0, 0);                                                         \
        }                                                                         \
    }

// One group: 12 MFMAs as SIX INDEPENDENT chains of depth 2 (3 limb-products x
// {A,B}), seeded {ci,0,0}, summed at the end. Same FLOPs/traffic as the old
// 2x depth-6 version; 3x the independent MFMA streams per wave.
#define COMPUTE(CH0, CH1, CL0, CL1, CIV, G) {                                       \
        f32x4 _z = {0.f, 0.f, 0.f, 0.f};                                            \
        f32x4 aS = __builtin_amdgcn_mfma_f32_16x16x32_f16(CH0, tsA0, CIV, 0,0,0);   \
        f32x4 bS = __builtin_amdgcn_mfma_f32_16x16x32_f16(CH0, tsB0, CIV, 0,0,0);   \
        f32x4 aH = __builtin_amdgcn_mfma_f32_16x16x32_f16(CL0, thA0, _z, 0,0,0);    \
        f32x4 bH = __builtin_amdgcn_mfma_f32_16x16x32_f16(CL0, thB0, _z, 0,0,0);    \
        f32x4 aL = __builtin_amdgcn_mfma_f32_16x16x32_f16(CH0, tlA0, _z, 0,0,0);    \
        f32x4 bL = __builtin_amdgcn_mfma_f32_16x16x32_f16(CH0, tlB0, _z, 0,0,0);    \
        aS = __builtin_amdgcn_mfma_f32_16x16x32_f16(CH1, tsA1, aS, 0,0,0);          \
        bS = __builtin_amdgcn_mfma_f32_16x16x32_f16(CH1, tsB1, bS, 0,0,0);          \
        aH = __builtin_amdgcn_mfma_f32_16x16x32_f16(CL1, thA1, aH, 0,0,0);          \
        bH = __builtin_amdgcn_mfma_f32_16x16x32_f16(CL1, thB1, bH, 0,0,0);          \
        aL = __builtin_amdgcn_mfma_f32_16x16x32_f16(CH1, tlA1, aL, 0,0,0);          \
        bL = __builtin_amdgcn_mfma_f32_16x16x32_f16(CH1, tlB1, bL, 0,0,0);          \
        f32x4 accA = (aS + aH) + aL;                                                \
        f32x4 accB = (bS + bH) + bL;                                                \
        const int base = (G) * 16 + quad4;                                          \
        _Pragma("unroll")                                                           \
        for (int i = 0; i < 4; ++i) {                                               \
            if (accA[i] > bvA) { bvA = accA[i]; biA = base + i; }                   \
            if (accB[i] > bvB) { bvB = accB[i]; biB = base + i; }                   \
        }                                                                           \
    }

    // prologue: stage chunk 0 of stage 0
    STAGE(0, 0);
    __syncthreads();
    int cur = 0;

    for (int q = 0; q < QS; ++q) {
        const float* cfq = cbf + (size_t)q * KS * DIM;

        float bvA = -INFINITY, bvB = -INFINITY;
        int   biA = 0,         biB = 0;

        for (int ch = 0; ch < 16; ++ch) {
            const int gc = (q << 4) | ch;
            if (gc + 1 < 128) STAGE(gc + 1, cur ^ 1);   // prefetch next chunk

            const _Float16* L   = smem + cur * CHUNK_H + lane * 8;
            const float*    dcL = (const float*)(smem + cur * CHUNK_H + DC2_OFF_H);
            const int gbase = ch * 4;

            // dc2 seeds: 4 ds_reads up front (broadcast within quad, no conflict)
            f32x4 ci0 = *(const f32x4*)(dcL +  0 + quad4);
            f32x4 ci1 = *(const f32x4*)(dcL + 16 + quad4);
            f32x4 ci2 = *(const f32x4*)(dcL + 32 + quad4);
            f32x4 ci3 = *(const f32x4*)(dcL + 48 + quad4);

            // register double-buffer over the chunk's 4 groups (ds_read_b128)
            f16x8 c0h0 = *(const f16x8*)(L);
            f16x8 c0h1 = *(const f16x8*)(L + 512);
            f16x8 c0l0 = *(const f16x8*)(L + 1024);
            f16x8 c0l1 = *(const f16x8*)(L + 1536);

            f16x8 c1h0 = *(const f16x8*)(L + 2048);
            f16x8 c1h1 = *(const f16x8*)(L + 2560);
            f16x8 c1l0 = *(const f16x8*)(L + 3072);
            f16x8 c1l1 = *(const f16x8*)(L + 3584);

            COMPUTE(c0h0, c0h1, c0l0, c0l1, ci0, gbase + 0);

            c0h0 = *(const f16x8*)(L + 4096);
            c0h1 = *(const f16x8*)(L + 4608);
            c0l0 = *(const f16x8*)(L + 5120);
            c0l1 = *(const f16x8*)(L + 5632);

            COMPUTE(c1h0, c1h1, c1l0, c1l1, ci1, gbase + 1);

            c1h0 = *(const f16x8*)(L + 6144);
            c1h1 = *(const f16x8*)(L + 6656);
            c1l0 = *(const f16x8*)(L + 7168);
            c1l1 = *(const f16x8*)(L + 7680);

            COMPUTE(c0h0, c0h1, c0l0, c0l1, ci2, gbase + 2);
            COMPUTE(c1h0, c1h1, c1l0, c1l1, ci3, gbase + 3);

            // barrier doubles as vmcnt/lgkm drain: staged chunk gc+1 resident,
            // all waves done reading buffer cur.
            __syncthreads();
            cur ^= 1;
        }

        // reduce over the 4 quad-lanes holding the same token (disjoint codewords):
        // 2 shuffle steps. Tie-break: lowest index, matching jnp.argmin.
#pragma unroll
        for (int mask = 16; mask <= 32; mask <<= 1) {
            float ovA = __shfl_xor(bvA, mask, 64);
            int   oiA = __shfl_xor(biA, mask, 64);
            if (ovA > bvA || (ovA == bvA && oiA < biA)) { bvA = ovA; biA = oiA; }
            float ovB = __shfl_xor(bvB, mask, 64);
            int   oiB = __shfl_xor(biB, mask, 64);
            if (ovB > bvB || (ovB == bvB && oiB < biB)) { bvB = ovB; biB = oiB; }
        }

        // indices straight to global (every lane already has its token's winner)
        if (quad == 0)      out[(size_t)N_TOK * DIM + (size_t)tokA * QS + q] = (float)biA;
        else if (quad == 1) out[(size_t)N_TOK * DIM + (size_t)tokB * QS + q] = (float)biB;

        // residual update: reconstruct r from limbs, subtract fp32 codeword, re-split
        float ls = 0.f;
        {
            const float* cp = cfq + (size_t)biA * DIM + quad * 8;
            f32x4 c0 = *(const f32x4*)(cp);
            f32x4 c1 = *(const f32x4*)(cp + 4);
            f32x4 c2 = *(const f32x4*)(cp + 32);
            f32x4 c3 = *(const f32x4*)(cp + 36);
#pragma unroll
            for (int j = 0; j < 4; ++j) {
                float v0 = fmaf(RISCALE, (float)tlA0[j],   (float)thA0[j])   - c0[j];
                float v1 = fmaf(RISCALE, (float)tlA0[j+4], (float)thA0[j+4]) - c1[j];
                float v2 = fmaf(RISCALE, (float)tlA1[j],   (float)thA1[j])   - c2[j];
                float v3 = fmaf(RISCALE, (float)tlA1[j+4], (float)thA1[j+4]) - c3[j];
                ls = fmaf(v0, v0, ls); ls = fmaf(v1, v1, ls);
                ls = fmaf(v2, v2, ls); ls = fmaf(v3, v3, ls);
                SPLIT3(v0, thA0[j],   tlA0[j],   tsA0[j]);
                SPLIT3(v1, thA0[j+4], tlA0[j+4], tsA0[j+4]);
                SPLIT3(v2, thA1[j],   tlA1[j],   tsA1[j]);
                SPLIT3(v3, thA1[j+4], tlA1[j+4], tsA1[j+4]);
            }
        }
        {
            const float* cp = cfq + (size_t)biB * DIM + quad * 8;
            f32x4 c0 = *(const f32x4*)(cp);
            f32x4 c1 = *(const f32x4*)(cp + 4);
            f32x4 c2 = *(const f32x4*)(cp + 32);
            f32x4 c3 = *(const f32x4*)(cp + 36);
#pragma unroll
            for (int j = 0; j < 4; ++j) {
                float v0 = fmaf(RISCALE, (float)tlB0[j],   (float)thB0[j])   - c0[j];
                float v1 = fmaf(RISCALE, (float)tlB0[j+4], (float)thB0[j+4]) - c1[j];
                float v2 = fmaf(RISCALE, (float)tlB1[j],   (float)thB1[j])   - c2[j];
                float v3 = fmaf(RISCALE, (float)tlB1[j+4], (float)thB1[j+4]) - c3[j];
                ls = fmaf(v0, v0, ls); ls = fmaf(v1, v1, ls);
                ls = fmaf(v2, v2, ls); ls = fmaf(v3, v3, ls);
                SPLIT3(v0, thB0[j],   tlB0[j],   tsB0[j]);
                SPLIT3(v1, thB0[j+4], tlB0[j+4], tsB0[j+4]);
                SPLIT3(v2, thB1[j],   tlB1[j],   tsB1[j]);
                SPLIT3(v3, thB1[j+4], tlB1[j+4], tsB1[j+4]);
            }
        }
#pragma unroll
        for (int mask = 1; mask <= 32; mask <<= 1) ls += __shfl_xor(ls, mask, 64);
        if (lane == 0)
            atomicAdd(out + (size_t)N_TOK * DIM + (size_t)N_TOK * QS + q,
                      ls * (1.0f / ((float)N_TOK * (float)DIM)));
    }

    // xq = x - r_final (reconstruct final residual from limbs)
    {
        const size_t ra = (size_t)tokA * DIM + quad * 8;
        const size_t rb = (size_t)tokB * DIM + quad * 8;
        f32x4 a0 = __builtin_nontemporal_load((const f32x4*)(x + ra));
        f32x4 a1 = __builtin_nontemporal_load((const f32x4*)(x + ra + 4));
        f32x4 a2 = __builtin_nontemporal_load((const f32x4*)(x + ra + 32));
        f32x4 a3 = __builtin_nontemporal_load((const f32x4*)(x + ra + 36));
        f32x4 b0 = __builtin_nontemporal_load((const f32x4*)(x + rb));
        f32x4 b1 = __builtin_nontemporal_load((const f32x4*)(x + rb + 4));
        f32x4 b2 = __builtin_nontemporal_load((const f32x4*)(x + rb + 32));
        f32x4 b3 = __builtin_nontemporal_load((const f32x4*)(x + rb + 36));
#pragma unroll
        for (int j = 0; j < 4; ++j) {
            a0[j] -= fmaf(RISCALE, (float)tlA0[j],   (float)thA0[j]);
            a1[j] -= fmaf(RISCALE, (float)tlA0[j+4], (float)thA0[j+4]);
            a2[j] -= fmaf(RISCALE, (float)tlA1[j],   (float)thA1[j]);
            a3[j] -= fmaf(RISCALE, (float)tlA1[j+4], (float)thA1[j+4]);
            b0[j] -= fmaf(RISCALE, (float)tlB0[j],   (float)thB0[j]);
            b1[j] -= fmaf(RISCALE, (float)tlB0[j+4], (float)thB0[j+4]);
            b2[j] -= fmaf(RISCALE, (float)tlB1[j],   (float)thB1[j]);
            b3[j] -= fmaf(RISCALE, (float)tlB1[j+4], (float)thB1[j+4]);
        }
        __builtin_nontemporal_store(a0, (f32x4*)(out + ra));
        __builtin_nontemporal_store(a1, (f32x4*)(out + ra + 4));
        __builtin_nontemporal_store(a2, (f32x4*)(out + ra + 32));
        __builtin_nontemporal_store(a3, (f32x4*)(out + ra + 36));
        __builtin_nontemporal_store(b0, (f32x4*)(out + rb));
        __builtin_nontemporal_store(b1, (f32x4*)(out + rb + 4));
        __builtin_nontemporal_store(b2, (f32x4*)(out + rb + 32));
        __builtin_nontemporal_store(b3, (f32x4*)(out + rb + 36));
    }
#undef COMPUTE
#undef STAGE
}

extern "C" void kernel_launch(void* const* d_in, const int* in_sizes, int n_in,
                              void* d_out, int out_size, void* d_ws, size_t ws_size,
                              hipStream_t stream) {
    const float* x   = (const float*)d_in[0];   // (N, D)
    const float* cb  = (const float*)d_in[1];   // (Q, K, D)
    float*       out = (float*)d_out;           // [xq | indices | losses]
    char*        ws  = (char*)d_ws;

    _Float16* G = (_Float16*)ws;   // 128 chunks x 16640 B = 2,129,920 B

    hipMemsetAsync(out + (size_t)N_TOK * DIM + (size_t)N_TOK * QS, 0,
                   QS * sizeof(float), stream);

    conv_kernel<<<512, 256, 0, stream>>>(cb, G);
    dc2_kernel<<<(QS * KS + 255) / 256, 256, 0, stream>>>(cb, (float*)ws);
    rvq_mfma_kernel<<<N_TOK / 128, 256, 0, stream>>>(x, cb, G, out);
}

// Round 5
// 575.504 us; speedup vs baseline: 1.6821x; 1.0399x over previous
//
#include <hip/hip_runtime.h>
#include <math.h>

#define N_TOK 131072
#define DIM   64
#define QS    8
#define KS    1024

typedef _Float16 f16x8 __attribute__((ext_vector_type(8)));
typedef float    f32x4 __attribute__((ext_vector_type(4)));

#define RSCALE   2048.0f
#define RISCALE  4.8828125e-4f   // 2^-11

// split fp32 v into f16 limbs + scaled-hi: v ~= hi + lo*2^-11 ; hs = 2048*hi (exact)
#define SPLIT3(v, hi, lo, hs) { _Float16 _h = (_Float16)(v); (hi) = _h;        \
                                (lo) = (_Float16)(((v) - (float)_h) * RSCALE); \
                                (hs) = (_Float16)((float)_h * RSCALE); }

// ---- workspace layout G: 128 chunks, each 16640 B:
//   [0    .. 16383]  frag limbs: 16 sub-slots of 1KB (4 groups x {h0,h1,l0,l1})
//   [16384.. 16639]  64 floats: -1024*||c||^2 seeds for the chunk's 64 codewords
// Chunk c covers stage q = c>>4, codewords (c&15)*64 .. +63.

// ---- pre-pass 1: codebook -> f16 limbs in MFMA fragment order.
// slot = (q*64+g)*4 + l*2 + h ; chunk c = slot>>4, sub = slot&15.
__global__ void conv_kernel(const float* __restrict__ cb, _Float16* __restrict__ G) {
    int t = blockIdx.x * blockDim.x + threadIdx.x;
    if (t >= 2048 * 64) return;
    const int lane = t & 63, slot = t >> 6;
    const int h = slot & 1, l = (slot >> 1) & 1, g = (slot >> 2) & 63, q = slot >> 8;
    const int cw = g * 16 + (lane & 15);
    const int d0 = h * 32 + (lane >> 4) * 8;
    const float* src = cb + ((size_t)q * KS + cw) * DIM + d0;
    f16x8 v;
#pragma unroll
    for (int j = 0; j < 8; ++j) {
        float c = src[j];
        _Float16 hi = (_Float16)c;
        v[j] = (l == 0) ? hi : (_Float16)((c - (float)hi) * RSCALE);
    }
    const int c = slot >> 4, w = slot & 15;
    *(f16x8*)(G + (size_t)c * 8320 + w * 512 + lane * 8) = v;
}

// ---- pre-pass 2: dc2 seeds written straight into each chunk's tail ----
__global__ void dc2_kernel(const float* __restrict__ cb, float* __restrict__ Gf) {
    int i = blockIdx.x * blockDim.x + threadIdx.x;
    if (i < QS * KS) {
        const float* c = cb + (size_t)i * DIM;
        float s = 0.f;
#pragma unroll
        for (int d = 0; d < DIM; ++d) s = fmaf(c[d], c[d], s);
        const int q = i >> 10, k = i & 1023;
        const int ch = q * 16 + (k >> 6), j = k & 63;
        Gf[(size_t)ch * 4160 + 4096 + j] = -1024.0f * s;
    }
}

#define CHUNK_B   16640     // bytes per chunk (16KB frags + 256B dc2)
#define CHUNK_H   8320      // _Float16 elements per chunk
#define DC2_OFF_H 8192      // half-offset of dc2 region (byte 16384)

// launch_bounds(256,2): VGPR cap 256 so the ENTIRE chunk's operands (16 frags
// + 4 seeds = 80 VGPRs) can be live at once. At (256,4)/64-VGPR the compiler
// emitted just-in-time ds_read -> lgkmcnt(0) -> MFMA round-trips (~8000 cyc
// of serialized latency per chunk) — the measured 36%-MfmaUtil wall.
__global__ __launch_bounds__(256, 2)
void rvq_mfma_kernel(const float* __restrict__ x,
                     const float* __restrict__ cbf,
                     const _Float16* __restrict__ F,
                     float* __restrict__ out) {
    __shared__ __attribute__((aligned(16))) _Float16 smem[2 * CHUNK_H]; // 33.3 KB

    const int tid  = threadIdx.x;
    const int wave = tid >> 6;
    const int lane = tid & 63;
    const int quad = lane >> 4;
    const int m    = lane & 15;
    const int quad4 = quad * 4;

    const int tokenBase = blockIdx.x * 128 + wave * 32;
    const int tokA = tokenBase + m, tokB = tokenBase + 16 + m;

    // token limbs (B-frag layout): th = hi, tl = 2048*(r-hi), ts = 2048*hi
    f16x8 thA0, thA1, tlA0, tlA1, tsA0, tsA1;
    f16x8 thB0, thB1, tlB0, tlB1, tsB0, tsB1;
    {
        const float* xa = x + (size_t)tokA * DIM + quad * 8;
        const float* xb = x + (size_t)tokB * DIM + quad * 8;
        f32x4 a0 = __builtin_nontemporal_load((const f32x4*)(xa));
        f32x4 a1 = __builtin_nontemporal_load((const f32x4*)(xa + 4));
        f32x4 a2 = __builtin_nontemporal_load((const f32x4*)(xa + 32));
        f32x4 a3 = __builtin_nontemporal_load((const f32x4*)(xa + 36));
        f32x4 b0 = __builtin_nontemporal_load((const f32x4*)(xb));
        f32x4 b1 = __builtin_nontemporal_load((const f32x4*)(xb + 4));
        f32x4 b2 = __builtin_nontemporal_load((const f32x4*)(xb + 32));
        f32x4 b3 = __builtin_nontemporal_load((const f32x4*)(xb + 36));
#pragma unroll
        for (int j = 0; j < 4; ++j) {
            SPLIT3(a0[j], thA0[j],   tlA0[j],   tsA0[j]);
            SPLIT3(a1[j], thA0[j+4], tlA0[j+4], tsA0[j+4]);
            SPLIT3(a2[j], thA1[j],   tlA1[j],   tsA1[j]);
            SPLIT3(a3[j], thA1[j+4], tlA1[j+4], tsA1[j+4]);
            SPLIT3(b0[j], thB0[j],   tlB0[j],   tsB0[j]);
            SPLIT3(b1[j], thB0[j+4], tlB0[j+4], tsB0[j+4]);
            SPLIT3(b2[j], thB1[j],   tlB1[j],   tsB1[j]);
            SPLIT3(b3[j], thB1[j+4], tlB1[j+4], tsB1[j+4]);
        }
    }

// stage one full chunk (frags + dc2 tail) of G into LDS buffer BUF.
// dest = wave-uniform base (+ lane*size implicit); global src is per-lane.
#define STAGE(GC, BUF) {                                                          \
        const char* _gs = (const char*)F + (size_t)(GC) * CHUNK_B                 \
                          + (wave << 10) + (lane << 4);                           \
        _Float16* _ld = smem + (BUF) * CHUNK_H + (wave << 9);                     \
        _Pragma("unroll")                                                         \
        for (int _j = 0; _j < 4; ++_j)                                            \
            __builtin_amdgcn_global_load_lds(                                     \
                (const __attribute__((address_space(1))) void*)(_gs + _j * 4096), \
                (__attribute__((address_space(3))) void*)(_ld + _j * 2048),       \
                16, 0, 0);                                                        \
        if (wave == 0) {                                                          \
            const char* _gd = (const char*)F + (size_t)(GC) * CHUNK_B + 16384     \
                              + (lane << 2);                                      \
            __builtin_amdgcn_global_load_lds(                                     \
                (const __attribute__((address_space(1))) void*)_gd,               \
                (__attribute__((address_space(3))) void*)(smem + (BUF) * CHUNK_H  \
                                                          + DC2_OFF_H),           \
                4, 0, 0);                                                         \
        }                                                                         \
    }

// One group: 2 chains of 6 MFMA; acc IS the scaled score, no VALU combine.
#define COMPUTE(CH0, CH1, CL0, CL1, CIV, G) {                                       \
        f32x4 accA = __builtin_amdgcn_mfma_f32_16x16x32_f16(CH0, tsA0, CIV, 0,0,0); \
        f32x4 accB = __builtin_amdgcn_mfma_f32_16x16x32_f16(CH0, tsB0, CIV, 0,0,0); \
        accA = __builtin_amdgcn_mfma_f32_16x16x32_f16(CH1, tsA1, accA, 0,0,0);      \
        accB = __builtin_amdgcn_mfma_f32_16x16x32_f16(CH1, tsB1, accB, 0,0,0);      \
        accA = __builtin_amdgcn_mfma_f32_16x16x32_f16(CL0, thA0, accA, 0,0,0);      \
        accB = __builtin_amdgcn_mfma_f32_16x16x32_f16(CL0, thB0, accB, 0,0,0);      \
        accA = __builtin_amdgcn_mfma_f32_16x16x32_f16(CL1, thA1, accA, 0,0,0);      \
        accB = __builtin_amdgcn_mfma_f32_16x16x32_f16(CL1, thB1, accB, 0,0,0);      \
        accA = __builtin_amdgcn_mfma_f32_16x16x32_f16(CH0, tlA0, accA, 0,0,0);      \
        accB = __builtin_amdgcn_mfma_f32_16x16x32_f16(CH0, tlB0, accB, 0,0,0);      \
        accA = __builtin_amdgcn_mfma_f32_16x16x32_f16(CH1, tlA1, accA, 0,0,0);      \
        accB = __builtin_amdgcn_mfma_f32_16x16x32_f16(CH1, tlB1, accB, 0,0,0);      \
        const int base = (G) * 16 + quad4;                                          \
        _Pragma("unroll")                                                           \
        for (int i = 0; i < 4; ++i) {                                               \
            if (accA[i] > bvA) { bvA = accA[i]; biA = base + i; }                   \
            if (accB[i] > bvB) { bvB = accB[i]; biB = base + i; }                   \
        }                                                                           \
    }

    // prologue: stage chunk 0 of stage 0
    STAGE(0, 0);
    __syncthreads();
    int cur = 0;

    for (int q = 0; q < QS; ++q) {
        const float* cfq = cbf + (size_t)q * KS * DIM;

        float bvA = -INFINITY, bvB = -INFINITY;
        int   biA = 0,         biB = 0;

        for (int ch = 0; ch < 16; ++ch) {
            const int gc = (q << 4) | ch;
            if (gc + 1 < 128) STAGE(gc + 1, cur ^ 1);   // prefetch next chunk

            const _Float16* L   = smem + cur * CHUNK_H + lane * 8;
            const float*    dcL = (const float*)(smem + cur * CHUNK_H + DC2_OFF_H);
            const int gbase = ch * 4;

            // ---- load the ENTIRE chunk's operands into registers up front:
            // 16 ds_read_b128 (frags) + 4 ds_read (seeds), all independent.
            f32x4 ci0 = *(const f32x4*)(dcL +  0 + quad4);
            f32x4 ci1 = *(const f32x4*)(dcL + 16 + quad4);
            f32x4 ci2 = *(const f32x4*)(dcL + 32 + quad4);
            f32x4 ci3 = *(const f32x4*)(dcL + 48 + quad4);

            f16x8 c0h0 = *(const f16x8*)(L);
            f16x8 c0h1 = *(const f16x8*)(L + 512);
            f16x8 c0l0 = *(const f16x8*)(L + 1024);
            f16x8 c0l1 = *(const f16x8*)(L + 1536);

            f16x8 c1h0 = *(const f16x8*)(L + 2048);
            f16x8 c1h1 = *(const f16x8*)(L + 2560);
            f16x8 c1l0 = *(const f16x8*)(L + 3072);
            f16x8 c1l1 = *(const f16x8*)(L + 3584);

            f16x8 c2h0 = *(const f16x8*)(L + 4096);
            f16x8 c2h1 = *(const f16x8*)(L + 4608);
            f16x8 c2l0 = *(const f16x8*)(L + 5120);
            f16x8 c2l1 = *(const f16x8*)(L + 5632);

            f16x8 c3h0 = *(const f16x8*)(L + 6144);
            f16x8 c3h1 = *(const f16x8*)(L + 6656);
            f16x8 c3l0 = *(const f16x8*)(L + 7168);
            f16x8 c3l1 = *(const f16x8*)(L + 7680);

            // fence: keep all loads issued above, all MFMAs below
            __builtin_amdgcn_sched_barrier(0);

            COMPUTE(c0h0, c0h1, c0l0, c0l1, ci0, gbase + 0);
            COMPUTE(c1h0, c1h1, c1l0, c1l1, ci1, gbase + 1);
            COMPUTE(c2h0, c2h1, c2l0, c2l1, ci2, gbase + 2);
            COMPUTE(c3h0, c3h1, c3l0, c3l1, ci3, gbase + 3);

            // barrier doubles as vmcnt/lgkm drain: staged chunk gc+1 resident,
            // all waves done reading buffer cur.
            __syncthreads();
            cur ^= 1;
        }

        // reduce over the 4 quad-lanes holding the same token (disjoint codewords):
        // 2 shuffle steps. Tie-break: lowest index, matching jnp.argmin.
#pragma unroll
        for (int mask = 16; mask <= 32; mask <<= 1) {
            float ovA = __shfl_xor(bvA, mask, 64);
            int   oiA = __shfl_xor(biA, mask, 64);
            if (ovA > bvA || (ovA == bvA && oiA < biA)) { bvA = ovA; biA = oiA; }
            float ovB = __shfl_xor(bvB, mask, 64);
            int   oiB = __shfl_xor(biB, mask, 64);
            if (ovB > bvB || (ovB == bvB && oiB < biB)) { bvB = ovB; biB = oiB; }
        }

        // indices straight to global (every lane already has its token's winner)
        if (quad == 0)      out[(size_t)N_TOK * DIM + (size_t)tokA * QS + q] = (float)biA;
        else if (quad == 1) out[(size_t)N_TOK * DIM + (size_t)tokB * QS + q] = (float)biB;

        // residual update: reconstruct r from limbs, subtract fp32 codeword, re-split
        float ls = 0.f;
        {
            const float* cp = cfq + (size_t)biA * DIM + quad * 8;
            f32x4 c0 = *(const f32x4*)(cp);
            f32x4 c1 = *(const f32x4*)(cp + 4);
            f32x4 c2 = *(const f32x4*)(cp + 32);
            f32x4 c3 = *(const f32x4*)(cp + 36);
#pragma unroll
            for (int j = 0; j < 4; ++j) {
                float v0 = fmaf(RISCALE, (float)tlA0[j],   (float)thA0[j])   - c0[j];
                float v1 = fmaf(RISCALE, (float)tlA0[j+4], (float)thA0[j+4]) - c1[j];
                float v2 = fmaf(RISCALE, (float)tlA1[j],   (float)thA1[j])   - c2[j];
                float v3 = fmaf(RISCALE, (float)tlA1[j+4], (float)thA1[j+4]) - c3[j];
                ls = fmaf(v0, v0, ls); ls = fmaf(v1, v1, ls);
                ls = fmaf(v2, v2, ls); ls = fmaf(v3, v3, ls);
                SPLIT3(v0, thA0[j],   tlA0[j],   tsA0[j]);
                SPLIT3(v1, thA0[j+4], tlA0[j+4], tsA0[j+4]);
                SPLIT3(v2, thA1[j],   tlA1[j],   tsA1[j]);
                SPLIT3(v3, thA1[j+4], tlA1[j+4], tsA1[j+4]);
            }
        }
        {
            const float* cp = cfq + (size_t)biB * DIM + quad * 8;
            f32x4 c0 = *(const f32x4*)(cp);
            f32x4 c1 = *(const f32x4*)(cp + 4);
            f32x4 c2 = *(const f32x4*)(cp + 32);
            f32x4 c3 = *(const f32x4*)(cp + 36);
#pragma unroll
            for (int j = 0; j < 4; ++j) {
                float v0 = fmaf(RISCALE, (float)tlB0[j],   (float)thB0[j])   - c0[j];
                float v1 = fmaf(RISCALE, (float)tlB0[j+4], (float)thB0[j+4]) - c1[j];
                float v2 = fmaf(RISCALE, (float)tlB1[j],   (float)thB1[j])   - c2[j];
                float v3 = fmaf(RISCALE, (float)tlB1[j+4], (float)thB1[j+4]) - c3[j];
                ls = fmaf(v0, v0, ls); ls = fmaf(v1, v1, ls);
                ls = fmaf(v2, v2, ls); ls = fmaf(v3, v3, ls);
                SPLIT3(v0, thB0[j],   tlB0[j],   tsB0[j]);
                SPLIT3(v1, thB0[j+4], tlB0[j+4], tsB0[j+4]);
                SPLIT3(v2, thB1[j],   tlB1[j],   tsB1[j]);
                SPLIT3(v3, thB1[j+4], tlB1[j+4], tsB1[j+4]);
            }
        }
#pragma unroll
        for (int mask = 1; mask <= 32; mask <<= 1) ls += __shfl_xor(ls, mask, 64);
        if (lane == 0)
            atomicAdd(out + (size_t)N_TOK * DIM + (size_t)N_TOK * QS + q,
                      ls * (1.0f / ((float)N_TOK * (float)DIM)));
    }

    // xq = x - r_final (reconstruct final residual from limbs)
    {
        const size_t ra = (size_t)tokA * DIM + quad * 8;
        const size_t rb = (size_t)tokB * DIM + quad * 8;
        f32x4 a0 = __builtin_nontemporal_load((const f32x4*)(x + ra));
        f32x4 a1 = __builtin_nontemporal_load((const f32x4*)(x + ra + 4));
        f32x4 a2 = __builtin_nontemporal_load((const f32x4*)(x + ra + 32));
        f32x4 a3 = __builtin_nontemporal_load((const f32x4*)(x + ra + 36));
        f32x4 b0 = __builtin_nontemporal_load((const f32x4*)(x + rb));
        f32x4 b1 = __builtin_nontemporal_load((const f32x4*)(x + rb + 4));
        f32x4 b2 = __builtin_nontemporal_load((const f32x4*)(x + rb + 32));
        f32x4 b3 = __builtin_nontemporal_load((const f32x4*)(x + rb + 36));
#pragma unroll
        for (int j = 0; j < 4; ++j) {
            a0[j] -= fmaf(RISCALE, (float)tlA0[j],   (float)thA0[j]);
            a1[j] -= fmaf(RISCALE, (float)tlA0[j+4], (float)thA0[j+4]);
            a2[j] -= fmaf(RISCALE, (float)tlA1[j],   (float)thA1[j]);
            a3[j] -= fmaf(RISCALE, (float)tlA1[j+4], (float)thA1[j+4]);
            b0[j] -= fmaf(RISCALE, (float)tlB0[j],   (float)thB0[j]);
            b1[j] -= fmaf(RISCALE, (float)tlB0[j+4], (float)thB0[j+4]);
            b2[j] -= fmaf(RISCALE, (float)tlB1[j],   (float)thB1[j]);
            b3[j] -= fmaf(RISCALE, (float)tlB1[j+4], (float)thB1[j+4]);
        }
        __builtin_nontemporal_store(a0, (f32x4*)(out + ra));
        __builtin_nontemporal_store(a1, (f32x4*)(out + ra + 4));
        __builtin_nontemporal_store(a2, (f32x4*)(out + ra + 32));
        __builtin_nontemporal_store(a3, (f32x4*)(out + ra + 36));
        __builtin_nontemporal_store(b0, (f32x4*)(out + rb));
        __builtin_nontemporal_store(b1, (f32x4*)(out + rb + 4));
        __builtin_nontemporal_store(b2, (f32x4*)(out + rb + 32));
        __builtin_nontemporal_store(b3, (f32x4*)(out + rb + 36));
    }
#undef COMPUTE
#undef STAGE
}

extern "C" void kernel_launch(void* const* d_in, const int* in_sizes, int n_in,
                              void* d_out, int out_size, void* d_ws, size_t ws_size,
                              hipStream_t stream) {
    const float* x   = (const float*)d_in[0];   // (N, D)
    const float* cb  = (const float*)d_in[1];   // (Q, K, D)
    float*       out = (float*)d_out;           // [xq | indices | losses]
    char*        ws  = (char*)d_ws;

    _Float16* G = (_Float16*)ws;   // 128 chunks x 16640 B = 2,129,920 B

    hipMemsetAsync(out + (size_t)N_TOK * DIM + (size_t)N_TOK * QS, 0,
                   QS * sizeof(float), stream);

    conv_kernel<<<512, 256, 0, stream>>>(cb, G);
    dc2_kernel<<<(QS * KS + 255) / 256, 256, 0, stream>>>(cb, (float*)ws);
    rvq_mfma_kernel<<<N_TOK / 128, 256, 0, stream>>>(x, cb, G, out);
}

// Round 6
// 440.575 us; speedup vs baseline: 2.1973x; 1.3063x over previous
//
#include <hip/hip_runtime.h>
#include <math.h>

#define N_TOK 131072
#define DIM   64
#define QS    8
#define KS    1024

typedef _Float16 f16x8 __attribute__((ext_vector_type(8)));
typedef float    f32x4 __attribute__((ext_vector_type(4)));

#define RSCALE   2048.0f
#define RISCALE  4.8828125e-4f   // 2^-11

// split fp32 v into f16 limbs + scaled-hi: v ~= hi + lo*2^-11 ; hs = 2048*hi (exact)
#define SPLIT3(v, hi, lo, hs) { _Float16 _h = (_Float16)(v); (hi) = _h;        \
                                (lo) = (_Float16)(((v) - (float)_h) * RSCALE); \
                                (hs) = (_Float16)((float)_h * RSCALE); }

// ---- workspace layout G: 128 chunks, each 16640 B:
//   [0    .. 16383]  frag limbs: 16 sub-slots of 1KB (4 groups x {h0,h1,l0,l1})
//   [16384.. 16639]  64 floats: -1024*||c||^2 seeds for the chunk's 64 codewords
// Chunk c covers stage q = c>>4, codewords (c&15)*64 .. +63.

// ---- pre-pass 1: codebook -> f16 limbs in MFMA fragment order.
// slot = (q*64+g)*4 + l*2 + h ; chunk c = slot>>4, sub = slot&15.
__global__ void conv_kernel(const float* __restrict__ cb, _Float16* __restrict__ G) {
    int t = blockIdx.x * blockDim.x + threadIdx.x;
    if (t >= 2048 * 64) return;
    const int lane = t & 63, slot = t >> 6;
    const int h = slot & 1, l = (slot >> 1) & 1, g = (slot >> 2) & 63, q = slot >> 8;
    const int cw = g * 16 + (lane & 15);
    const int d0 = h * 32 + (lane >> 4) * 8;
    const float* src = cb + ((size_t)q * KS + cw) * DIM + d0;
    f16x8 v;
#pragma unroll
    for (int j = 0; j < 8; ++j) {
        float c = src[j];
        _Float16 hi = (_Float16)c;
        v[j] = (l == 0) ? hi : (_Float16)((c - (float)hi) * RSCALE);
    }
    const int c = slot >> 4, w = slot & 15;
    *(f16x8*)(G + (size_t)c * 8320 + w * 512 + lane * 8) = v;
}

// ---- pre-pass 2: dc2 seeds written straight into each chunk's tail ----
__global__ void dc2_kernel(const float* __restrict__ cb, float* __restrict__ Gf) {
    int i = blockIdx.x * blockDim.x + threadIdx.x;
    if (i < QS * KS) {
        const float* c = cb + (size_t)i * DIM;
        float s = 0.f;
#pragma unroll
        for (int d = 0; d < DIM; ++d) s = fmaf(c[d], c[d], s);
        const int q = i >> 10, k = i & 1023;
        const int ch = q * 16 + (k >> 6), j = k & 63;
        Gf[(size_t)ch * 4160 + 4096 + j] = -1024.0f * s;
    }
}

#define CHUNK_B   16640     // bytes per chunk (16KB frags + 256B dc2)
#define CHUNK_H   8320      // _Float16 elements per chunk
#define DC2_OFF_H 8192      // half-offset of dc2 region (byte 16384)

// ---- main: 4 TOKEN-SETS PER WAVE (64 tokens/wave, 256/block, grid 512).
// All 5 prior rounds pinned at ~33 B/cyc/CU of operand load-return traffic
// regardless of source/occupancy/scheduling; the lever is bytes-per-MFMA.
// Each 4KB fragment group now feeds 4 token-sets (24 MFMAs) instead of 2 (12),
// halving load traffic per MFMA. Per-token numerics identical to before.
__global__ __launch_bounds__(256, 2)
void rvq_mfma_kernel(const float* __restrict__ x,
                     const float* __restrict__ cbf,
                     const _Float16* __restrict__ F,
                     float* __restrict__ out) {
    __shared__ __attribute__((aligned(16))) _Float16 smem[2 * CHUNK_H]; // 33.3 KB

    const int tid  = threadIdx.x;
    const int wave = tid >> 6;
    const int lane = tid & 63;
    const int quad = lane >> 4;
    const int m    = lane & 15;
    const int quad4 = quad * 4;

    const int tokenBase = blockIdx.x * 256 + wave * 64;

    // token limbs, 4 sets (B-frag layout): th = hi, tl = 2048*(r-hi), ts = 2048*hi
    f16x8 th00, th01, tl00, tl01, ts00, ts01;
    f16x8 th10, th11, tl10, tl11, ts10, ts11;
    f16x8 th20, th21, tl20, tl21, ts20, ts21;
    f16x8 th30, th31, tl30, tl31, ts30, ts31;

#define LOADTOK(S, TH0, TH1, TL0, TL1, TS0, TS1) {                                \
        const float* xa = x + (size_t)(tokenBase + (S) * 16 + m) * DIM + quad * 8;\
        f32x4 a0 = __builtin_nontemporal_load((const f32x4*)(xa));                \
        f32x4 a1 = __builtin_nontemporal_load((const f32x4*)(xa + 4));            \
        f32x4 a2 = __builtin_nontemporal_load((const f32x4*)(xa + 32));           \
        f32x4 a3 = __builtin_nontemporal_load((const f32x4*)(xa + 36));           \
        _Pragma("unroll")                                                         \
        for (int j = 0; j < 4; ++j) {                                             \
            SPLIT3(a0[j], TH0[j],   TL0[j],   TS0[j]);                            \
            SPLIT3(a1[j], TH0[j+4], TL0[j+4], TS0[j+4]);                          \
            SPLIT3(a2[j], TH1[j],   TL1[j],   TS1[j]);                            \
            SPLIT3(a3[j], TH1[j+4], TL1[j+4], TS1[j+4]);                          \
        }                                                                         \
    }
    LOADTOK(0, th00, th01, tl00, tl01, ts00, ts01);
    LOADTOK(1, th10, th11, tl10, tl11, ts10, ts11);
    LOADTOK(2, th20, th21, tl20, tl21, ts20, ts21);
    LOADTOK(3, th30, th31, tl30, tl31, ts30, ts31);

// stage one full chunk (frags + dc2 tail) of G into LDS buffer BUF.
// dest = wave-uniform base (+ lane*size implicit); global src is per-lane.
#define STAGE(GC, BUF) {                                                          \
        const char* _gs = (const char*)F + (size_t)(GC) * CHUNK_B                 \
                          + (wave << 10) + (lane << 4);                           \
        _Float16* _ld = smem + (BUF) * CHUNK_H + (wave << 9);                     \
        _Pragma("unroll")                                                         \
        for (int _j = 0; _j < 4; ++_j)                                            \
            __builtin_amdgcn_global_load_lds(                                     \
                (const __attribute__((address_space(1))) void*)(_gs + _j * 4096), \
                (__attribute__((address_space(3))) void*)(_ld + _j * 2048),       \
                16, 0, 0);                                                        \
        if (wave == 0) {                                                          \
            const char* _gd = (const char*)F + (size_t)(GC) * CHUNK_B + 16384     \
                              + (lane << 2);                                      \
            __builtin_amdgcn_global_load_lds(                                     \
                (const __attribute__((address_space(1))) void*)_gd,               \
                (__attribute__((address_space(3))) void*)(smem + (BUF) * CHUNK_H  \
                                                          + DC2_OFF_H),           \
                4, 0, 0);                                                         \
        }                                                                         \
    }

// One group: 24 MFMAs = 4 independent depth-6 chains (one per token-set),
// all sharing the same codeword fragments. acc IS the scaled score.
#define COMPUTE(CH0, CH1, CL0, CL1, CIV, G) {                                       \
        f32x4 A0 = __builtin_amdgcn_mfma_f32_16x16x32_f16(CH0, ts00, CIV, 0,0,0);   \
        f32x4 A1 = __builtin_amdgcn_mfma_f32_16x16x32_f16(CH0, ts10, CIV, 0,0,0);   \
        f32x4 A2 = __builtin_amdgcn_mfma_f32_16x16x32_f16(CH0, ts20, CIV, 0,0,0);   \
        f32x4 A3 = __builtin_amdgcn_mfma_f32_16x16x32_f16(CH0, ts30, CIV, 0,0,0);   \
        A0 = __builtin_amdgcn_mfma_f32_16x16x32_f16(CH1, ts01, A0, 0,0,0);          \
        A1 = __builtin_amdgcn_mfma_f32_16x16x32_f16(CH1, ts11, A1, 0,0,0);          \
        A2 = __builtin_amdgcn_mfma_f32_16x16x32_f16(CH1, ts21, A2, 0,0,0);          \
        A3 = __builtin_amdgcn_mfma_f32_16x16x32_f16(CH1, ts31, A3, 0,0,0);          \
        A0 = __builtin_amdgcn_mfma_f32_16x16x32_f16(CL0, th00, A0, 0,0,0);          \
        A1 = __builtin_amdgcn_mfma_f32_16x16x32_f16(CL0, th10, A1, 0,0,0);          \
        A2 = __builtin_amdgcn_mfma_f32_16x16x32_f16(CL0, th20, A2, 0,0,0);          \
        A3 = __builtin_amdgcn_mfma_f32_16x16x32_f16(CL0, th30, A3, 0,0,0);          \
        A0 = __builtin_amdgcn_mfma_f32_16x16x32_f16(CL1, th01, A0, 0,0,0);          \
        A1 = __builtin_amdgcn_mfma_f32_16x16x32_f16(CL1, th11, A1, 0,0,0);          \
        A2 = __builtin_amdgcn_mfma_f32_16x16x32_f16(CL1, th21, A2, 0,0,0);          \
        A3 = __builtin_amdgcn_mfma_f32_16x16x32_f16(CL1, th31, A3, 0,0,0);          \
        A0 = __builtin_amdgcn_mfma_f32_16x16x32_f16(CH0, tl00, A0, 0,0,0);          \
        A1 = __builtin_amdgcn_mfma_f32_16x16x32_f16(CH0, tl10, A1, 0,0,0);          \
        A2 = __builtin_amdgcn_mfma_f32_16x16x32_f16(CH0, tl20, A2, 0,0,0);          \
        A3 = __builtin_amdgcn_mfma_f32_16x16x32_f16(CH0, tl30, A3, 0,0,0);          \
        A0 = __builtin_amdgcn_mfma_f32_16x16x32_f16(CH1, tl01, A0, 0,0,0);          \
        A1 = __builtin_amdgcn_mfma_f32_16x16x32_f16(CH1, tl11, A1, 0,0,0);          \
        A2 = __builtin_amdgcn_mfma_f32_16x16x32_f16(CH1, tl21, A2, 0,0,0);          \
        A3 = __builtin_amdgcn_mfma_f32_16x16x32_f16(CH1, tl31, A3, 0,0,0);          \
        const int base = (G) * 16 + quad4;                                          \
        _Pragma("unroll")                                                           \
        for (int i = 0; i < 4; ++i) {                                               \
            if (A0[i] > bv0) { bv0 = A0[i]; bi0 = base + i; }                       \
            if (A1[i] > bv1) { bv1 = A1[i]; bi1 = base + i; }                       \
            if (A2[i] > bv2) { bv2 = A2[i]; bi2 = base + i; }                       \
            if (A3[i] > bv3) { bv3 = A3[i]; bi3 = base + i; }                       \
        }                                                                           \
    }

    // prologue: stage chunk 0 of stage 0
    STAGE(0, 0);
    __syncthreads();
    int cur = 0;

    for (int q = 0; q < QS; ++q) {
        const float* cfq = cbf + (size_t)q * KS * DIM;

        float bv0 = -INFINITY, bv1 = -INFINITY, bv2 = -INFINITY, bv3 = -INFINITY;
        int   bi0 = 0, bi1 = 0, bi2 = 0, bi3 = 0;

        for (int ch = 0; ch < 16; ++ch) {
            const int gc = (q << 4) | ch;
            if (gc + 1 < 128) STAGE(gc + 1, cur ^ 1);   // prefetch next chunk

            const _Float16* L   = smem + cur * CHUNK_H + lane * 8;
            const float*    dcL = (const float*)(smem + cur * CHUNK_H + DC2_OFF_H);
            const int gbase = ch * 4;

            // dc2 seeds up front (broadcast within quad, no conflict)
            f32x4 ci0 = *(const f32x4*)(dcL +  0 + quad4);
            f32x4 ci1 = *(const f32x4*)(dcL + 16 + quad4);
            f32x4 ci2 = *(const f32x4*)(dcL + 32 + quad4);
            f32x4 ci3 = *(const f32x4*)(dcL + 48 + quad4);

            // register double-buffer over the chunk's 4 groups (ds_read_b128)
            f16x8 g0h0 = *(const f16x8*)(L);
            f16x8 g0h1 = *(const f16x8*)(L + 512);
            f16x8 g0l0 = *(const f16x8*)(L + 1024);
            f16x8 g0l1 = *(const f16x8*)(L + 1536);

            f16x8 g1h0 = *(const f16x8*)(L + 2048);
            f16x8 g1h1 = *(const f16x8*)(L + 2560);
            f16x8 g1l0 = *(const f16x8*)(L + 3072);
            f16x8 g1l1 = *(const f16x8*)(L + 3584);

            COMPUTE(g0h0, g0h1, g0l0, g0l1, ci0, gbase + 0);

            g0h0 = *(const f16x8*)(L + 4096);
            g0h1 = *(const f16x8*)(L + 4608);
            g0l0 = *(const f16x8*)(L + 5120);
            g0l1 = *(const f16x8*)(L + 5632);

            COMPUTE(g1h0, g1h1, g1l0, g1l1, ci1, gbase + 1);

            g1h0 = *(const f16x8*)(L + 6144);
            g1h1 = *(const f16x8*)(L + 6656);
            g1l0 = *(const f16x8*)(L + 7168);
            g1l1 = *(const f16x8*)(L + 7680);

            COMPUTE(g0h0, g0h1, g0l0, g0l1, ci2, gbase + 2);
            COMPUTE(g1h0, g1h1, g1l0, g1l1, ci3, gbase + 3);

            // barrier doubles as vmcnt/lgkm drain: staged chunk gc+1 resident,
            // all waves done reading buffer cur.
            __syncthreads();
            cur ^= 1;
        }

        // reduce over the 4 quad-lanes holding the same token (disjoint codewords):
        // 2 shuffle steps. Tie-break: lowest index, matching jnp.argmin.
#define REDUCE(BV, BI) {                                                          \
        _Pragma("unroll")                                                         \
        for (int mask = 16; mask <= 32; mask <<= 1) {                             \
            float ov = __shfl_xor(BV, mask, 64);                                  \
            int   oi = __shfl_xor(BI, mask, 64);                                  \
            if (ov > BV || (ov == BV && oi < BI)) { BV = ov; BI = oi; }           \
        }                                                                         \
    }
        REDUCE(bv0, bi0); REDUCE(bv1, bi1); REDUCE(bv2, bi2); REDUCE(bv3, bi3);

        // index writes: quad s writes set s's token (64 lanes = 64 tokens)
        {
            const int myTok = tokenBase + quad * 16 + m;
            const int mybi  = (quad == 0) ? bi0 : (quad == 1) ? bi1
                            : (quad == 2) ? bi2 : bi3;
            out[(size_t)N_TOK * DIM + (size_t)myTok * QS + q] = (float)mybi;
        }

        // residual update per set: reconstruct r, subtract fp32 codeword, re-split
        float ls = 0.f;
#define RESID(BI, TH0, TH1, TL0, TL1, TS0, TS1) {                                 \
        const float* cp = cfq + (size_t)(BI) * DIM + quad * 8;                    \
        f32x4 c0 = *(const f32x4*)(cp);                                           \
        f32x4 c1 = *(const f32x4*)(cp + 4);                                       \
        f32x4 c2 = *(const f32x4*)(cp + 32);                                      \
        f32x4 c3 = *(const f32x4*)(cp + 36);                                      \
        _Pragma("unroll")                                                         \
        for (int j = 0; j < 4; ++j) {                                             \
            float v0 = fmaf(RISCALE, (float)TL0[j],   (float)TH0[j])   - c0[j];   \
            float v1 = fmaf(RISCALE, (float)TL0[j+4], (float)TH0[j+4]) - c1[j];   \
            float v2 = fmaf(RISCALE, (float)TL1[j],   (float)TH1[j])   - c2[j];   \
            float v3 = fmaf(RISCALE, (float)TL1[j+4], (float)TH1[j+4]) - c3[j];   \
            ls = fmaf(v0, v0, ls); ls = fmaf(v1, v1, ls);                         \
            ls = fmaf(v2, v2, ls); ls = fmaf(v3, v3, ls);                         \
            SPLIT3(v0, TH0[j],   TL0[j],   TS0[j]);                               \
            SPLIT3(v1, TH0[j+4], TL0[j+4], TS0[j+4]);                             \
            SPLIT3(v2, TH1[j],   TL1[j],   TS1[j]);                               \
            SPLIT3(v3, TH1[j+4], TL1[j+4], TS1[j+4]);                             \
        }                                                                         \
    }
        RESID(bi0, th00, th01, tl00, tl01, ts00, ts01);
        RESID(bi1, th10, th11, tl10, tl11, ts10, ts11);
        RESID(bi2, th20, th21, tl20, tl21, ts20, ts21);
        RESID(bi3, th30, th31, tl30, tl31, ts30, ts31);

#pragma unroll
        for (int mask = 1; mask <= 32; mask <<= 1) ls += __shfl_xor(ls, mask, 64);
        if (lane == 0)
            atomicAdd(out + (size_t)N_TOK * DIM + (size_t)N_TOK * QS + q,
                      ls * (1.0f / ((float)N_TOK * (float)DIM)));
    }

    // xq = x - r_final (reconstruct final residual from limbs), per set
#define XQW(S, TH0, TH1, TL0, TL1) {                                              \
        const size_t ra = (size_t)(tokenBase + (S) * 16 + m) * DIM + quad * 8;    \
        f32x4 a0 = __builtin_nontemporal_load((const f32x4*)(x + ra));            \
        f32x4 a1 = __builtin_nontemporal_load((const f32x4*)(x + ra + 4));        \
        f32x4 a2 = __builtin_nontemporal_load((const f32x4*)(x + ra + 32));       \
        f32x4 a3 = __builtin_nontemporal_load((const f32x4*)(x + ra + 36));       \
        _Pragma("unroll")                                                         \
        for (int j = 0; j < 4; ++j) {                                             \
            a0[j] -= fmaf(RISCALE, (float)TL0[j],   (float)TH0[j]);               \
            a1[j] -= fmaf(RISCALE, (float)TL0[j+4], (float)TH0[j+4]);             \
            a2[j] -= fmaf(RISCALE, (float)TL1[j],   (float)TH1[j]);               \
            a3[j] -= fmaf(RISCALE, (float)TL1[j+4], (float)TH1[j+4]);             \
        }                                                                         \
        __builtin_nontemporal_store(a0, (f32x4*)(out + ra));                      \
        __builtin_nontemporal_store(a1, (f32x4*)(out + ra + 4));                  \
        __builtin_nontemporal_store(a2, (f32x4*)(out + ra + 32));                 \
        __builtin_nontemporal_store(a3, (f32x4*)(out + ra + 36));                 \
    }
    XQW(0, th00, th01, tl00, tl01);
    XQW(1, th10, th11, tl10, tl11);
    XQW(2, th20, th21, tl20, tl21);
    XQW(3, th30, th31, tl30, tl31);

#undef COMPUTE
#undef STAGE
#undef LOADTOK
#undef REDUCE
#undef RESID
#undef XQW
}

extern "C" void kernel_launch(void* const* d_in, const int* in_sizes, int n_in,
                              void* d_out, int out_size, void* d_ws, size_t ws_size,
                              hipStream_t stream) {
    const float* x   = (const float*)d_in[0];   // (N, D)
    const float* cb  = (const float*)d_in[1];   // (Q, K, D)
    float*       out = (float*)d_out;           // [xq | indices | losses]
    char*        ws  = (char*)d_ws;

    _Float16* G = (_Float16*)ws;   // 128 chunks x 16640 B = 2,129,920 B

    hipMemsetAsync(out + (size_t)N_TOK * DIM + (size_t)N_TOK * QS, 0,
                   QS * sizeof(float), stream);

    conv_kernel<<<512, 256, 0, stream>>>(cb, G);
    dc2_kernel<<<(QS * KS + 255) / 256, 256, 0, stream>>>(cb, (float*)ws);
    rvq_mfma_kernel<<<N_TOK / 256, 256, 0, stream>>>(x, cb, G, out);
}